// Round 3
// baseline (166.946 us; speedup 1.0000x reference)
//
#include <hip/hip_runtime.h>

typedef __attribute__((ext_vector_type(8))) short bf16x8;
typedef __attribute__((ext_vector_type(4))) float f32x4;

#define AS1 __attribute__((address_space(1)))
#define AS3 __attribute__((address_space(3)))

__device__ static inline void gl2lds16(const void* g, void* l) {
  // async global->LDS, 16B per lane; HW writes wave-uniform base + lane*16
  __builtin_amdgcn_global_load_lds((const AS1 unsigned int*)g, (AS3 unsigned int*)l, 16, 0, 0);
}

__device__ static inline unsigned short f2bf(float x) {
  unsigned int u = __float_as_uint(x);
  unsigned int r = u + 0x7FFFu + ((u >> 16) & 1u);  // round-to-nearest-even
  return (unsigned short)(r >> 16);
}

// R11 prep: A-cast branch DELETED (A is now reg-staged inside the GEMM from
// raw f32 -> kills the 32MB write + 32MB re-read and 8192 of 9280 blocks).
//  bx < 1024   : code_book row cast -> b[1024][1024] bf16 + rowsum[1024]
//  bx >= 1024  : labels normalize (int64-vs-int32 autodetect); bx==1024,t==0 zeroes lin/out
__global__ __launch_bounds__(256) void prep_bl_k(
    const float* __restrict__ cb, const int* __restrict__ labraw,
    unsigned short* __restrict__ b, float* __restrict__ rowsum,
    int* __restrict__ labs, float* __restrict__ lin, float* __restrict__ out) {
  const int bx = blockIdx.x, t = threadIdx.x;
  if (bx < 1024) {
    int n = bx;
    float s = 0.f;
#pragma unroll
    for (int j = 0; j < 4; ++j) {
      int c = t + j * 256;
      float v = 0.f;
      if (n < 1000 && c < 1000) v = cb[(size_t)n * 1000 + c];
      s += v;
      b[((size_t)n << 10) + c] = f2bf(v);
    }
    __shared__ float red[256];
    red[t] = s;
    __syncthreads();
    for (int o = 128; o > 0; o >>= 1) {
      if (t < o) red[t] += red[t + o];
      __syncthreads();
    }
    if (t == 0) rowsum[n] = (n < 1000) ? red[0] : 0.f;
  } else {
    __shared__ int nz;
    if (t == 0) nz = 0;
    __syncthreads();
    if (labraw[2 * t + 1] != 0) atomicAdd(&nz, 1);
    __syncthreads();
    bool is64 = (nz < 32);
    int row = (bx - 1024) * 256 + t;
    labs[row] = is64 ? labraw[2 * row] : labraw[row];
    if (bx == 1024 && t == 0) { lin[0] = 0.f; out[0] = 0.f; }
  }
}

// R11: fused A-cast GEMM. Block 256x256, 8 waves (2x4), wave tile 128x64 =
// 8x4 MFMA 16x16x32 bf16 (acc 128 regs, 2 waves/SIMD). BK=32, 2-deep LDS
// double buffer = 64 KB static (A0,A1,B0,B1 x 16 KB).
// A path (new): reg-staged from raw f32 inputs. Per region J: issue 4x
// global_load_dwordx4 for tile J+1 (latency hides under ~1200cyc of
// reads+MFMA), then f2bf(2*x) convert (bit-identical to old prep) + 2x
// ds_write_b128 into the SAME swizzled layout (per-lane ds_write has full
// addressing freedom; read side unchanged). B path: gl_lds from prepped bf16
// (2-deep). Issue order A-loads then B-gl_lds -> the cvt's compiler-inserted
// vmcnt wait leaves B's loads in flight; __syncthreads drains the rest
// (B is L2-resident, cheap). Buffer parity: region J reads parity J&1,
// writes parity (J+1)&1 -> WAR-safe across the region barrier.
// R7 swizzle kept: LDS slot (row, c) holds global chunk c ^ ((row>>1)&3);
// staging thread t owns rows {t>>2, 128+(t>>2)}, slot t&3, global chunk
// sg = (t&3)^((t>>3)&3) (same for both rows since 128 is a multiple of 8).
// Tile-31 A-padding: cols 992..999 valid (sg==0), rest zero-filled via
// predicated loads (no OOB reads past inputs[16384*1000]).
__global__ __launch_bounds__(512, 2) void coding_loss_k(
    const float* __restrict__ In,           // [16384][1000] f32 raw inputs
    const unsigned short* __restrict__ Bg,  // [1024][1024] bf16 = code
    const float* __restrict__ rowsum,       // [1024]
    const int* __restrict__ labels,         // [16384] int32 (normalized)
    float* __restrict__ Z,                  // [4][16384] partial expsums
    float* __restrict__ lin) {              // scalar (zeroed by prep)
  __shared__ __align__(16) unsigned short lds[32768];  // 64 KB
  // A bufs: lds + p*8192, B bufs: lds + 16384 + p*8192, p = 0..1

  const int t    = threadIdx.x;
  const int lane = t & 63;
  const int w    = t >> 6;   // 0..7
  const int wr   = w >> 2;   // 0..1: rows wr*128..+128
  const int wc   = w & 3;    // 0..3: cols wc*64..+64
  const int g16  = lane >> 4;
  const int c16  = lane & 15;
  const int ct   = blockIdx.x & 3;
  const int rt   = blockIdx.x >> 2;
  const int r0   = rt << 8;
  const int c0   = ct << 8;

  // ---- staging maps ----
  const int sg  = (t & 3) ^ ((t >> 3) & 3);     // global 8-f32 chunk this thread fetches
  const int rA0 = t >> 2, rA1 = 128 + (t >> 2); // block-local rows owned
  const float* pA0 = In + (size_t)(r0 + rA0) * 1000 + sg * 8;
  const float* pA1 = In + (size_t)(r0 + rA1) * 1000 + sg * 8;
  // B: pre-swizzled global source, linear LDS dest (gl_lds writes base+lane*16)
  size_t b_src[2]; int bdst[2];
#pragma unroll
  for (int i = 0; i < 2; ++i) {
    int ch = i * 512 + t, row = ch >> 2;
    int sgb = (ch & 3) ^ ((row >> 1) & 3);
    b_src[i] = (size_t)(c0 + row) * 1024 + sgb * 8;
    bdst[i] = ch * 8;
  }
  // fragment LDS element offsets (within one buffer)
  int a_eoff[8], b_eoff[4];
#pragma unroll
  for (int i = 0; i < 8; ++i) {
    int ar = wr * 128 + i * 16 + c16;
    a_eoff[i] = ar * 32 + ((g16 ^ ((ar >> 1) & 3)) << 3);
  }
#pragma unroll
  for (int i = 0; i < 4; ++i) {
    int br = wc * 64 + i * 16 + c16;
    b_eoff[i] = br * 32 + ((g16 ^ ((br >> 1) & 3)) << 3);
  }

  f32x4 acc[8][4];
#pragma unroll
  for (int mi = 0; mi < 8; ++mi)
#pragma unroll
    for (int ni = 0; ni < 4; ++ni) acc[mi][ni] = (f32x4)(0.f);

#define LOADA(js, G0A, G0B, G1A, G1B)                                          \
  {                                                                            \
    if ((js) < 31 || sg == 0) {                                                \
      const float4* q0 = (const float4*)(pA0 + (js) * 32);                     \
      const float4* q1 = (const float4*)(pA1 + (js) * 32);                     \
      G0A = q0[0]; G0B = q0[1]; G1A = q1[0]; G1B = q1[1];                      \
    } else {                                                                   \
      G0A = G0B = G1A = G1B = make_float4(0.f, 0.f, 0.f, 0.f);                 \
    }                                                                          \
  }

#define CVWRA(p, G0A, G0B, G1A, G1B)                                           \
  {                                                                            \
    union { unsigned short u[8]; uint4 v; } w0, w1;                            \
    w0.u[0] = f2bf(2.f * G0A.x); w0.u[1] = f2bf(2.f * G0A.y);                  \
    w0.u[2] = f2bf(2.f * G0A.z); w0.u[3] = f2bf(2.f * G0A.w);                  \
    w0.u[4] = f2bf(2.f * G0B.x); w0.u[5] = f2bf(2.f * G0B.y);                  \
    w0.u[6] = f2bf(2.f * G0B.z); w0.u[7] = f2bf(2.f * G0B.w);                  \
    w1.u[0] = f2bf(2.f * G1A.x); w1.u[1] = f2bf(2.f * G1A.y);                  \
    w1.u[2] = f2bf(2.f * G1A.z); w1.u[3] = f2bf(2.f * G1A.w);                  \
    w1.u[4] = f2bf(2.f * G1B.x); w1.u[5] = f2bf(2.f * G1B.y);                  \
    w1.u[6] = f2bf(2.f * G1B.z); w1.u[7] = f2bf(2.f * G1B.w);                  \
    *(uint4*)(lds + ((p) << 13) + t * 8) = w0.v;                               \
    *(uint4*)(lds + ((p) << 13) + 4096 + t * 8) = w1.v;                        \
  }

#define COMPUTE(p)                                                             \
  {                                                                            \
    const unsigned short* pa = lds + ((p) << 13);                              \
    const unsigned short* pb = lds + 16384 + ((p) << 13);                      \
    bf16x8 af[4], af2[4], bv[4];                                               \
    _Pragma("unroll") for (int i = 0; i < 4; ++i)                              \
        af[i] = *(const bf16x8*)(pa + a_eoff[i]);                              \
    _Pragma("unroll") for (int i = 0; i < 4; ++i)                              \
        bv[i] = *(const bf16x8*)(pb + b_eoff[i]);                              \
    _Pragma("unroll") for (int i = 0; i < 4; ++i)                              \
        af2[i] = *(const bf16x8*)(pa + a_eoff[i + 4]);                         \
    _Pragma("unroll") for (int mi = 0; mi < 4; ++mi)                           \
      _Pragma("unroll") for (int ni = 0; ni < 4; ++ni)                         \
        acc[mi][ni] =                                                          \
            __builtin_amdgcn_mfma_f32_16x16x32_bf16(af[mi], bv[ni], acc[mi][ni], 0, 0, 0); \
    _Pragma("unroll") for (int mi = 0; mi < 4; ++mi)                           \
      _Pragma("unroll") for (int ni = 0; ni < 4; ++ni)                         \
        acc[mi + 4][ni] =                                                      \
            __builtin_amdgcn_mfma_f32_16x16x32_bf16(af2[mi], bv[ni], acc[mi + 4][ni], 0, 0, 0); \
  }

  // ---- prologue: tile 0 -> parity 0 ----
  {
    float4 g0a, g0b, g1a, g1b;
    LOADA(0, g0a, g0b, g1a, g1b);
    gl2lds16(Bg + b_src[0], lds + 16384 + bdst[0]);
    gl2lds16(Bg + b_src[1], lds + 16384 + bdst[1]);
    CVWRA(0, g0a, g0b, g1a, g1b);  // compiler inserts vmcnt wait for A loads
    __syncthreads();               // drains vmcnt(0)+lgkm; B0+A0 block-visible
  }

  // ---- main loop: region J computes tile J, stages tile J+1 ----
  for (int J = 0; J < 31; ++J) {
    const int jn = J + 1;
    float4 g0a, g0b, g1a, g1b;
    LOADA(jn, g0a, g0b, g1a, g1b);   // issue early; consumed at region end
    gl2lds16(Bg + b_src[0] + jn * 32, lds + 16384 + ((jn & 1) << 13) + bdst[0]);
    gl2lds16(Bg + b_src[1] + jn * 32, lds + 16384 + ((jn & 1) << 13) + bdst[1]);
    COMPUTE(J & 1);                  // ~1200 cyc: hides A-load + B-gl_lds latency
    CVWRA(jn & 1, g0a, g0b, g1a, g1b);
    __syncthreads();
  }
  COMPUTE(1);       // tile 31
  __syncthreads();  // drain before aliasing LDS for epilogue

  // ---- epilogue (zbuf aliases the staging LDS) ----
  float* zbuf = (float*)lds;   // [8 waves][128 rows]
  float* lbuf = zbuf + 1024;   // [8]
  float rs[4]; int gcol[4];
#pragma unroll
  for (int ni = 0; ni < 4; ++ni) {
    gcol[ni] = c0 + wc * 64 + ni * 16 + c16;
    rs[ni]   = rowsum[gcol[ni]];
  }
  float lacc = 0.f;  // 0.9*S_label + 1e-4*sum S
#pragma unroll
  for (int mi = 0; mi < 8; ++mi) {
#pragma unroll
    for (int r = 0; r < 4; ++r) {
      int lrow = mi * 16 + g16 * 4 + r;
      int labv = labels[r0 + wr * 128 + lrow];
      float e = 0.f;
#pragma unroll
      for (int ni = 0; ni < 4; ++ni) {
        float S = acc[mi][ni][r] - rs[ni];  // padded cols: S==0, harmless
        e += __expf(S - 40.f);
        lacc += 1e-4f * S;
        if (gcol[ni] == labv) lacc += 0.9f * S;
      }
      e += __shfl_xor(e, 1, 64);
      e += __shfl_xor(e, 2, 64);
      e += __shfl_xor(e, 4, 64);
      e += __shfl_xor(e, 8, 64);
      if (c16 == 0) zbuf[w * 128 + lrow] = e;
    }
  }
#pragma unroll
  for (int d = 1; d < 64; d <<= 1) lacc += __shfl_xor(lacc, d, 64);
  if (lane == 0) lbuf[w] = lacc;
  __syncthreads();
  if (t < 256) {  // row t of the 256-row block: sum the 4 wc wave slices
    int wrg = t >> 7, l7 = t & 127;
    float z = zbuf[(wrg * 4 + 0) * 128 + l7] + zbuf[(wrg * 4 + 1) * 128 + l7] +
              zbuf[(wrg * 4 + 2) * 128 + l7] + zbuf[(wrg * 4 + 3) * 128 + l7];
    Z[ct * 16384 + r0 + t] = z;  // single writer per slot
  }
  if (t == 0)
    atomicAdd(lin, lbuf[0] + lbuf[1] + lbuf[2] + lbuf[3] +
                   lbuf[4] + lbuf[5] + lbuf[6] + lbuf[7]);
#undef LOADA
#undef CVWRA
#undef COMPUTE
}

// out = mean_r(40 + log(sum_ct Z[ct][r])) - lin/16384
__global__ __launch_bounds__(256) void finalize_k(const float* __restrict__ Z,
                                                  const float* __restrict__ lin,
                                                  float* __restrict__ out) {
  int t = threadIdx.x;
  int row = blockIdx.x * 256 + t;
  float v = 40.f + logf(Z[row] + Z[16384 + row] + Z[2 * 16384 + row] + Z[3 * 16384 + row]);
#pragma unroll
  for (int d = 1; d < 64; d <<= 1) v += __shfl_xor(v, d, 64);
  __shared__ float s[4];
  if ((t & 63) == 0) s[t >> 6] = v;
  __syncthreads();
  if (t == 0) {
    float tot = s[0] + s[1] + s[2] + s[3];
    if (blockIdx.x == 0) tot -= lin[0];
    atomicAdd(out, tot * (1.f / 16384.f));
  }
}

extern "C" void kernel_launch(void* const* d_in, const int* in_sizes, int n_in,
                              void* d_out, int out_size, void* d_ws, size_t ws_size,
                              hipStream_t stream) {
  const float* inputs = (const float*)d_in[0];
  const int* labraw   = (const int*)d_in[1];
  const float* code   = (const float*)d_in[2];

  unsigned short* b_bf = (unsigned short*)d_ws;                 // 2 MB
  float* rowsum        = (float*)(b_bf + (size_t)1024 * 1024);  // 4 KB
  float* Z             = rowsum + 1024;                         // [4][16384] = 256 KB
  float* lin           = Z + 4 * 16384;                         // 4 B
  int* labs            = (int*)(lin + 1);                       // 64 KB

  // 3 graph nodes; prep shrank 9280 -> 1088 blocks (A-cast fused into GEMM)
  prep_bl_k<<<1088, 256, 0, stream>>>(code, labraw, b_bf, rowsum, labs, lin,
                                      (float*)d_out);
  coding_loss_k<<<256, 512, 0, stream>>>(inputs, b_bf, rowsum, labs, Z, lin);
  finalize_k<<<64, 256, 0, stream>>>(Z, lin, (float*)d_out);
}

// Round 4
// 155.250 us; speedup vs baseline: 1.0753x; 1.0753x over previous
//
#include <hip/hip_runtime.h>

typedef __attribute__((ext_vector_type(8))) short bf16x8;
typedef __attribute__((ext_vector_type(4))) float f32x4;

#define AS1 __attribute__((address_space(1)))
#define AS3 __attribute__((address_space(3)))

__device__ static inline void gl2lds16(const void* g, void* l) {
  // async global->LDS, 16B per lane; HW writes wave-uniform base + lane*16
  __builtin_amdgcn_global_load_lds((const AS1 unsigned int*)g, (AS3 unsigned int*)l, 16, 0, 0);
}

__device__ static inline unsigned short f2bf(float x) {
  unsigned int u = __float_as_uint(x);
  unsigned int r = u + 0x7FFFu + ((u >> 16) & 1u);  // round-to-nearest-even
  return (unsigned short)(r >> 16);
}

// Prep (A-cast stays fused into the GEMM):
//  bx < 1024   : code_book row cast -> b[1024][1024] bf16 + rowsum[1024]
//  bx >= 1024  : labels normalize (int64-vs-int32 autodetect); bx==1024,t==0 zeroes lin/out
__global__ __launch_bounds__(256) void prep_bl_k(
    const float* __restrict__ cb, const int* __restrict__ labraw,
    unsigned short* __restrict__ b, float* __restrict__ rowsum,
    int* __restrict__ labs, float* __restrict__ lin, float* __restrict__ out) {
  const int bx = blockIdx.x, t = threadIdx.x;
  if (bx < 1024) {
    int n = bx;
    float s = 0.f;
#pragma unroll
    for (int j = 0; j < 4; ++j) {
      int c = t + j * 256;
      float v = 0.f;
      if (n < 1000 && c < 1000) v = cb[(size_t)n * 1000 + c];
      s += v;
      b[((size_t)n << 10) + c] = f2bf(v);
    }
    __shared__ float red[256];
    red[t] = s;
    __syncthreads();
    for (int o = 128; o > 0; o >>= 1) {
      if (t < o) red[t] += red[t + o];
      __syncthreads();
    }
    if (t == 0) rowsum[n] = (n < 1000) ? red[0] : 0.f;
  } else {
    __shared__ int nz;
    if (t == 0) nz = 0;
    __syncthreads();
    if (labraw[2 * t + 1] != 0) atomicAdd(&nz, 1);
    __syncthreads();
    bool is64 = (nz < 32);
    int row = (bx - 1024) * 256 + t;
    labs[row] = is64 ? labraw[2 * row] : labraw[row];
    if (bx == 1024 && t == 0) { lin[0] = 0.f; out[0] = 0.f; }
  }
}

// R12: fused A-cast GEMM + XCD-chunked swizzle + counted-vmcnt pipeline.
// R11 post-mortem: (a) ct-siblings sharing A landed on 4 different XCDs ->
// per-XCD L2s each demand-fetched A (FETCH 68->134 MB, dur tracked at the
// same ~1.5 TB/s cross-XCD wall that capped every prior round); (b)
// __syncthreads() drained vmcnt(0) per region -> 1-deep pipeline.
// Fixes:
//  * Swizzle: HW round-robins blockIdx%8 across XCDs. L=(bid&7)*32+(bid>>3)
//    gives each XCD a contiguous 8rt x 4ct chunk: A panel read ONCE from HBM
//    (4 ct-siblings hit their own L2), B slice shared by 8 rt-siblings and
//    L3-resident chip-wide (2 MB unique). Per-XCD per-tile A slice = 256 KB
//    << 4 MB L2. Bijective (256 = 8*32).
//  * Raw s_barrier + counted waits. Region J: {issue gl_lds B(J+1); issue
//    A(J+2)->regs (named double-set float4, static indexing, 2-region
//    latency slack); COMPUTE(J); cvt+ds_write A(J+1) (compiler waits
//    vmcnt(6) for its own loads); s_waitcnt vmcnt(4) lgkmcnt(0) = B(J+1)
//    landed + ds_writes visible, A(J+2) still in flight; s_barrier}.
// Block 256x256, 8 waves (2x4), wave tile 128x64 = 8x4 MFMA 16x16x32 bf16.
// BK=32, 2-deep LDS (A0,A1,B0,B1 x 16 KB = 64 KB static).
// R7 swizzle kept: LDS slot (row,c) holds global chunk c ^ ((row>>1)&3);
// A-staging thread t owns rows {t>>2, 128+(t>>2)}, slot t&3, global chunk
// sg=(t&3)^((t>>3)&3). Tile-31 A cols 992..999 valid only for sg==0,
// predicated (no OOB past inputs[16384*1000]).
__global__ __launch_bounds__(512, 2) void coding_loss_k(
    const float* __restrict__ In,           // [16384][1000] f32 raw inputs
    const unsigned short* __restrict__ Bg,  // [1024][1024] bf16 = code
    const float* __restrict__ rowsum,       // [1024]
    const int* __restrict__ labels,         // [16384] int32 (normalized)
    float* __restrict__ Z,                  // [4][16384] partial expsums
    float* __restrict__ lin) {              // scalar (zeroed by prep)
  __shared__ __align__(16) unsigned short lds[32768];  // 64 KB
  // A bufs: lds + p*8192, B bufs: lds + 16384 + p*8192, p = 0..1

  const int t    = threadIdx.x;
  const int lane = t & 63;
  const int w    = t >> 6;   // 0..7
  const int wr   = w >> 2;   // 0..1: rows wr*128..+128
  const int wc   = w & 3;    // 0..3: cols wc*64..+64
  const int g16  = lane >> 4;
  const int c16  = lane & 15;
  // XCD-chunked bijective swizzle (8 XCDs x 32 blocks)
  const int bid  = blockIdx.x;
  const int L    = ((bid & 7) << 5) | (bid >> 3);
  const int ct   = L & 3;
  const int rt   = L >> 2;
  const int r0   = rt << 8;
  const int c0   = ct << 8;

  // ---- staging maps ----
  const int sg  = (t & 3) ^ ((t >> 3) & 3);     // global 8-f32 chunk this thread fetches
  const int rA0 = t >> 2, rA1 = 128 + (t >> 2); // block-local rows owned
  const float* pA0 = In + (size_t)(r0 + rA0) * 1000 + sg * 8;
  const float* pA1 = In + (size_t)(r0 + rA1) * 1000 + sg * 8;
  // B: pre-swizzled global source, linear LDS dest (gl_lds writes base+lane*16)
  size_t b_src[2]; int bdst[2];
#pragma unroll
  for (int i = 0; i < 2; ++i) {
    int ch = i * 512 + t, row = ch >> 2;
    int sgb = (ch & 3) ^ ((row >> 1) & 3);
    b_src[i] = (size_t)(c0 + row) * 1024 + sgb * 8;
    bdst[i] = ch * 8;
  }
  // fragment LDS element offsets (within one buffer)
  int a_eoff[8], b_eoff[4];
#pragma unroll
  for (int i = 0; i < 8; ++i) {
    int ar = wr * 128 + i * 16 + c16;
    a_eoff[i] = ar * 32 + ((g16 ^ ((ar >> 1) & 3)) << 3);
  }
#pragma unroll
  for (int i = 0; i < 4; ++i) {
    int br = wc * 64 + i * 16 + c16;
    b_eoff[i] = br * 32 + ((g16 ^ ((br >> 1) & 3)) << 3);
  }

  f32x4 acc[8][4];
#pragma unroll
  for (int mi = 0; mi < 8; ++mi)
#pragma unroll
    for (int ni = 0; ni < 4; ++ni) acc[mi][ni] = (f32x4)(0.f);

#define LOADA(js, R0, R1, R2, R3)                                              \
  {                                                                            \
    if ((js) < 31 || sg == 0) {                                                \
      const float4* q0 = (const float4*)(pA0 + (size_t)(js) * 32);             \
      const float4* q1 = (const float4*)(pA1 + (size_t)(js) * 32);             \
      R0 = q0[0]; R1 = q0[1]; R2 = q1[0]; R3 = q1[1];                          \
    } else {                                                                   \
      R0 = R1 = R2 = R3 = make_float4(0.f, 0.f, 0.f, 0.f);                     \
    }                                                                          \
  }

#define CVWRA(p, R0, R1, R2, R3)                                               \
  {                                                                            \
    union { unsigned short u[8]; uint4 v; } w0, w1;                            \
    w0.u[0] = f2bf(2.f * R0.x); w0.u[1] = f2bf(2.f * R0.y);                    \
    w0.u[2] = f2bf(2.f * R0.z); w0.u[3] = f2bf(2.f * R0.w);                    \
    w0.u[4] = f2bf(2.f * R1.x); w0.u[5] = f2bf(2.f * R1.y);                    \
    w0.u[6] = f2bf(2.f * R1.z); w0.u[7] = f2bf(2.f * R1.w);                    \
    w1.u[0] = f2bf(2.f * R2.x); w1.u[1] = f2bf(2.f * R2.y);                    \
    w1.u[2] = f2bf(2.f * R2.z); w1.u[3] = f2bf(2.f * R2.w);                    \
    w1.u[4] = f2bf(2.f * R3.x); w1.u[5] = f2bf(2.f * R3.y);                    \
    w1.u[6] = f2bf(2.f * R3.z); w1.u[7] = f2bf(2.f * R3.w);                    \
    *(uint4*)(lds + ((p) << 13) + t * 8) = w0.v;                               \
    *(uint4*)(lds + ((p) << 13) + 4096 + t * 8) = w1.v;                        \
  }

#define COMPUTE(p)                                                             \
  {                                                                            \
    const unsigned short* pa = lds + ((p) << 13);                              \
    const unsigned short* pb = lds + 16384 + ((p) << 13);                      \
    bf16x8 af[4], af2[4], bv[4];                                               \
    _Pragma("unroll") for (int i = 0; i < 4; ++i)                              \
        af[i] = *(const bf16x8*)(pa + a_eoff[i]);                              \
    _Pragma("unroll") for (int i = 0; i < 4; ++i)                              \
        bv[i] = *(const bf16x8*)(pb + b_eoff[i]);                              \
    _Pragma("unroll") for (int i = 0; i < 4; ++i)                              \
        af2[i] = *(const bf16x8*)(pa + a_eoff[i + 4]);                         \
    _Pragma("unroll") for (int mi = 0; mi < 4; ++mi)                           \
      _Pragma("unroll") for (int ni = 0; ni < 4; ++ni)                         \
        acc[mi][ni] =                                                          \
            __builtin_amdgcn_mfma_f32_16x16x32_bf16(af[mi], bv[ni], acc[mi][ni], 0, 0, 0); \
    _Pragma("unroll") for (int mi = 0; mi < 4; ++mi)                           \
      _Pragma("unroll") for (int ni = 0; ni < 4; ++ni)                         \
        acc[mi + 4][ni] =                                                      \
            __builtin_amdgcn_mfma_f32_16x16x32_bf16(af2[mi], bv[ni], acc[mi + 4][ni], 0, 0, 0); \
  }

// Region J: reads LDS parity J&1, fills parity (J+1)&1. Consumes A(J+1) from
// reg set C*, loads A(J+2) into reg set L* (2-region latency slack).
// End wait vmcnt(4): B(J+1)'s 2 gl_lds + consumed A's 4 loads drained,
// A(J+2)'s 4 loads untouched. lgkmcnt(0): ds_writes visible after barrier.
#define REGION(J, C0, C1, C2, C3, L0, L1, L2, L3, DOLOAD, WAITIMM)             \
  {                                                                            \
    const int jn = (J) + 1;                                                    \
    gl2lds16(Bg + b_src[0] + jn * 32, lds + 16384 + ((jn & 1) << 13) + bdst[0]); \
    gl2lds16(Bg + b_src[1] + jn * 32, lds + 16384 + ((jn & 1) << 13) + bdst[1]); \
    if (DOLOAD) { LOADA((J) + 2, L0, L1, L2, L3); }                            \
    __builtin_amdgcn_sched_barrier(0);                                         \
    COMPUTE((J) & 1);                                                          \
    __builtin_amdgcn_sched_barrier(0);                                         \
    CVWRA(jn & 1, C0, C1, C2, C3);                                             \
    __builtin_amdgcn_sched_barrier(0);                                         \
    __builtin_amdgcn_s_waitcnt(WAITIMM);                                       \
    __builtin_amdgcn_s_barrier();                                              \
    __builtin_amdgcn_sched_barrier(0);                                         \
  }

  float4 g0a, g0b, g1a, g1b;  // reg set 0: holds A(js) with js even
  float4 h0a, h0b, h1a, h1b;  // reg set 1: holds A(js) with js odd

  // ---- prologue: tile 0 -> parity 0; prefetch A(1) ----
  gl2lds16(Bg + b_src[0], lds + 16384 + bdst[0]);
  gl2lds16(Bg + b_src[1], lds + 16384 + bdst[1]);
  LOADA(0, g0a, g0b, g1a, g1b);
  LOADA(1, h0a, h0b, h1a, h1b);
  CVWRA(0, g0a, g0b, g1a, g1b);  // compiler waits vmcnt(4): A(0) done
  __builtin_amdgcn_sched_barrier(0);
  __builtin_amdgcn_s_waitcnt(0x074);  // vmcnt(4) lgkmcnt(0): B(0)+A(0) done, A(1) in flight
  __builtin_amdgcn_s_barrier();
  __builtin_amdgcn_sched_barrier(0);

  // ---- main loop: region J computes tile J, stages tile J+1 ----
  for (int j2 = 0; j2 < 15; ++j2) {
    const int J = j2 * 2;
    REGION(J,     h0a, h0b, h1a, h1b, g0a, g0b, g1a, g1b, 1, 0x074);
    REGION(J + 1, g0a, g0b, g1a, g1b, h0a, h0b, h1a, h1b, 1, 0x074);
  }
  REGION(30, h0a, h0b, h1a, h1b, g0a, g0b, g1a, g1b, 0, 0x070);  // vmcnt(0)
  COMPUTE(1);       // tile 31
  __syncthreads();  // drain before aliasing LDS for epilogue

  // ---- epilogue (zbuf aliases the staging LDS) ----
  float* zbuf = (float*)lds;   // [8 waves][128 rows]
  float* lbuf = zbuf + 1024;   // [8]
  float rs[4]; int gcol[4];
#pragma unroll
  for (int ni = 0; ni < 4; ++ni) {
    gcol[ni] = c0 + wc * 64 + ni * 16 + c16;
    rs[ni]   = rowsum[gcol[ni]];
  }
  float lacc = 0.f;  // 0.9*S_label + 1e-4*sum S
#pragma unroll
  for (int mi = 0; mi < 8; ++mi) {
#pragma unroll
    for (int r = 0; r < 4; ++r) {
      int lrow = mi * 16 + g16 * 4 + r;
      int labv = labels[r0 + wr * 128 + lrow];
      float e = 0.f;
#pragma unroll
      for (int ni = 0; ni < 4; ++ni) {
        float S = acc[mi][ni][r] - rs[ni];  // padded cols: S==0, harmless
        e += __expf(S - 40.f);
        lacc += 1e-4f * S;
        if (gcol[ni] == labv) lacc += 0.9f * S;
      }
      e += __shfl_xor(e, 1, 64);
      e += __shfl_xor(e, 2, 64);
      e += __shfl_xor(e, 4, 64);
      e += __shfl_xor(e, 8, 64);
      if (c16 == 0) zbuf[w * 128 + lrow] = e;
    }
  }
#pragma unroll
  for (int d = 1; d < 64; d <<= 1) lacc += __shfl_xor(lacc, d, 64);
  if (lane == 0) lbuf[w] = lacc;
  __syncthreads();
  if (t < 256) {  // row t of the 256-row block: sum the 4 wc wave slices
    int wrg = t >> 7, l7 = t & 127;
    float z = zbuf[(wrg * 4 + 0) * 128 + l7] + zbuf[(wrg * 4 + 1) * 128 + l7] +
              zbuf[(wrg * 4 + 2) * 128 + l7] + zbuf[(wrg * 4 + 3) * 128 + l7];
    Z[ct * 16384 + r0 + t] = z;  // single writer per slot
  }
  if (t == 0)
    atomicAdd(lin, lbuf[0] + lbuf[1] + lbuf[2] + lbuf[3] +
                   lbuf[4] + lbuf[5] + lbuf[6] + lbuf[7]);
#undef LOADA
#undef CVWRA
#undef COMPUTE
#undef REGION
}

// out = mean_r(40 + log(sum_ct Z[ct][r])) - lin/16384
__global__ __launch_bounds__(256) void finalize_k(const float* __restrict__ Z,
                                                  const float* __restrict__ lin,
                                                  float* __restrict__ out) {
  int t = threadIdx.x;
  int row = blockIdx.x * 256 + t;
  float v = 40.f + logf(Z[row] + Z[16384 + row] + Z[2 * 16384 + row] + Z[3 * 16384 + row]);
#pragma unroll
  for (int d = 1; d < 64; d <<= 1) v += __shfl_xor(v, d, 64);
  __shared__ float s[4];
  if ((t & 63) == 0) s[t >> 6] = v;
  __syncthreads();
  if (t == 0) {
    float tot = s[0] + s[1] + s[2] + s[3];
    if (blockIdx.x == 0) tot -= lin[0];
    atomicAdd(out, tot * (1.f / 16384.f));
  }
}

extern "C" void kernel_launch(void* const* d_in, const int* in_sizes, int n_in,
                              void* d_out, int out_size, void* d_ws, size_t ws_size,
                              hipStream_t stream) {
  const float* inputs = (const float*)d_in[0];
  const int* labraw   = (const int*)d_in[1];
  const float* code   = (const float*)d_in[2];

  unsigned short* b_bf = (unsigned short*)d_ws;                 // 2 MB
  float* rowsum        = (float*)(b_bf + (size_t)1024 * 1024);  // 4 KB
  float* Z             = rowsum + 1024;                         // [4][16384] = 256 KB
  float* lin           = Z + 4 * 16384;                         // 4 B
  int* labs            = (int*)(lin + 1);                       // 64 KB

  // 3 graph nodes; A-cast fused into GEMM, prep is 1088 blocks (~6 MB traffic)
  prep_bl_k<<<1088, 256, 0, stream>>>(code, labraw, b_bf, rowsum, labs, lin,
                                      (float*)d_out);
  coding_loss_k<<<256, 512, 0, stream>>>(inputs, b_bf, rowsum, labs, Z, lin);
  finalize_k<<<64, 256, 0, stream>>>(Z, lin, (float*)d_out);
}